// Round 6
// baseline (468.416 us; speedup 1.0000x reference)
//
#include <hip/hip_runtime.h>

typedef unsigned short ushort_t;
typedef __attribute__((ext_vector_type(8))) __bf16 bf16x8;
typedef __attribute__((ext_vector_type(4))) float f32x4;

#define SEQ 8192
#define DIN 1024
#define DOUT 1024

// epilogue output modes
#define OM_BF16 0
#define OM_EXP  2   // bf16 exp2(scale*acc) store + per-block partial row-sums -> rsp
#define OM_NORM 3   // f32 store of acc * invrs[row]

__device__ __forceinline__ ushort_t f2bf(float f) {
  union { float f; unsigned u; } c; c.f = f;
  unsigned u = c.u;
  return (ushort_t)((u + 0x7fffu + ((u >> 16) & 1u)) >> 16);  // RNE
}

__device__ __forceinline__ void async16(ushort_t* lds, const ushort_t* g) {
  __builtin_amdgcn_global_load_lds(
      (__attribute__((address_space(1))) void*)g,
      (__attribute__((address_space(3))) void*)lds, 16, 0, 0);
}

template <int N>
__device__ __forceinline__ void waitv() {
  asm volatile("s_waitcnt vmcnt(%0)" :: "n"(N) : "memory");
}

__device__ __forceinline__ void lgkm0() {
  // memory clobber: pins each phase's ds_reads above this point (no sinking,
  // no hoisting into earlier phases past the previous phase's lgkm0/vmcnt)
  asm volatile("s_waitcnt lgkmcnt(0)" ::: "memory");
}

// ------- fused fp32 -> bf16 convert for x, Wq, Wk, Wv -------
__global__ __launch_bounds__(256) void cvt_all_kernel(
    const float* __restrict__ x, const float* __restrict__ wq,
    const float* __restrict__ wk, const float* __restrict__ wv,
    ushort_t* __restrict__ xb, ushort_t* __restrict__ wqkb,
    ushort_t* __restrict__ wvb) {
  int b = blockIdx.x;
  const float* src;
  ushort_t* dst;
  int idx;
  if (b < 8192) {
    src = x; dst = xb; idx = b * 256 + threadIdx.x;
  } else {
    int r = b - 8192;
    int w = r >> 10;
    idx = (r & 1023) * 256 + threadIdx.x;
    if (w == 0)      { src = wq; dst = wqkb; }
    else if (w == 1) { src = wk; dst = wqkb + DOUT * DIN; }
    else             { src = wv; dst = wvb; }
  }
  float4 f = ((const float4*)src)[idx];
  ushort4 o;
  o.x = f2bf(f.x); o.y = f2bf(f.y); o.z = f2bf(f.z); o.w = f2bf(f.w);
  ((ushort4*)dst)[idx] = o;
}

// ------- rowsum partials [32][SEQ] -> invrs[SEQ] = 1/sum -------
__global__ __launch_bounds__(256) void rowsum_inv_kernel(const float* __restrict__ rsp,
                                                         float* __restrict__ invrs) {
  int r = blockIdx.x * 256 + threadIdx.x;
  float s = 0.f;
  #pragma unroll
  for (int p2 = 0; p2 < 32; ++p2) s += rsp[p2 * SEQ + r];
  invrs[r] = 1.0f / s;
}

// ---------------- GEMM: C[M][N] = A[M][K] @ B[N][K]^T ----------------
// Round-6: m201-pure 8-phase schedule on the round-4 skeleton.
// BMxBN tile, BK=64, 512 thr = 8 waves (2M x 4N), wave tile (BM/2)x(BN/4),
// mfma_f32_16x16x32_bf16. Phases are C-QUADRANTS x K=64:
//   P1(q00): read A-lo(ks0,1) + B-lo(ks0,1); P2(q01): read B-hi;
//   P3(q10): read A-hi; P4(q11): no reads.
// Phase body: {reads, stage 1 half, s_barrier, lgkmcnt(0), setprio(1) MFMA
// setprio(0), s_barrier}. NO sched_barrier anywhere (m141: order-pinning
// regressed 42%); the only fences are the lgkm0/vmcnt memory clobbers, which
// keep every phase's reads inside the phase.
// Zero loop VALU for reads: row===r16 (mod 8) makes the swizzled chunk slot
// lane-constant per ks, so all 24 ds_reads/tile are 4 precomputed base
// pointers + compile-time immediates (mi*2048B, +tile*2*AST B; all < 64 KiB).
// Stage plan (round-4, proven): P1:O.Ah0 P2:O.Ah1 P3:E2.Bh0 P4:E2.Bh1
//                               P5:E2.Ah0 P6:E2.Ah1 P7:O2.Bh0 P8:O2.Bh1
// vmcnt(2*LB) at end of P4/P8 -> exactly the two newest B-halves stay in
// flight; tile buffers are block-wide valid after the closing barrier.
// Stage-over-reader safety (quadrant reads): buf1.A-lo last read P5(prev
// iter), staged P1 (barriers P6..P8 between); buf1.A-hi last read P7-prev,
// staged P2; buf0.B last read P2, staged P3/P4 (P2-end barrier between);
// mirror for P5..P8. All separated by >=1 barrier + lgkm-complete.
template <int OUTMODE, int SUPER, int BM, int BN>
__global__ __launch_bounds__(512, 2) void gemmq(
    const ushort_t* __restrict__ A, const ushort_t* __restrict__ B,
    void* __restrict__ C, int lda, int ldb, int ldc, int K, float scale,
    float* __restrict__ rsp, const float* __restrict__ invrs) {
  constexpr int WM = BM / 2, WN = BN / 4;
  constexpr int MI = BM / 32, NIfr = BN / 64;
  constexpr int MH = MI / 2, NH = NIfr / 2;   // quadrant sizes
  constexpr int AST = BM * 64, BST = BN * 64;
  constexpr int AHALF = AST / 2, BHALF = BST / 2;
  constexpr int LA = BM / 128, LB = BN / 128; // loads/thread per half
  __shared__ ushort_t As[2 * AST];
  __shared__ ushort_t Bs[2 * BST];

  const int t = threadIdx.x;
  const int lane = t & 63;
  const int wave = t >> 6;
  const int wr = wave >> 2, wc = wave & 3;
  const int quad = lane >> 4, r16 = lane & 15;

  const int gx = gridDim.x;
  const int nwg = gx * gridDim.y;
  const int bid = blockIdx.y * gx + blockIdx.x;
  int mt, nt;
  if (SUPER == 1) {
    // 32x32 grid only: XCD (x>>2, x&3) owns 16mt x 8nt, walked in 4x8 chunks
    int x = bid & 7, l = bid >> 3;
    mt = ((x >> 2) << 4) + ((l >> 5) << 2) + ((l >> 3) & 3);
    nt = ((x & 3) << 3) + (l & 7);
  } else {
    const int q8 = nwg >> 3;
    const int b2 = (bid & 7) * q8 + (bid >> 3);
    mt = b2 / gx;
    nt = b2 - mt * gx;
  }
  const int rowBase = mt * BM;
  const int colBase = nt * BN;

  // staging source offsets (elements), one set per {operand, half}; +64/use
  unsigned offA[2][LA], offB[2][LB];
  #pragma unroll
  for (int h = 0; h < 2; ++h) {
    #pragma unroll
    for (int i = 0; i < LA; ++i) {
      int c = t + i * 512, row = c >> 3, sl = c & 7;
      offA[h][i] = (unsigned)((rowBase + h * (BM / 2) + row) * lda +
                              ((sl ^ (row & 7)) << 3));
    }
    #pragma unroll
    for (int i = 0; i < LB; ++i) {
      int c = t + i * 512, row = c >> 3, sl = c & 7;
      offB[h][i] = (unsigned)((colBase + h * (BN / 2) + row) * ldb +
                              ((sl ^ (row & 7)) << 3));
    }
  }

  auto stageA = [&](int buf, int h) {
    #pragma unroll
    for (int i = 0; i < LA; ++i) {
      async16(&As[buf * AST + h * AHALF + (t + i * 512) * 8], A + offA[h][i]);
      offA[h][i] += 64;
    }
  };
  auto stageB = [&](int buf, int h) {
    #pragma unroll
    for (int i = 0; i < LB; ++i) {
      async16(&Bs[buf * BST + h * BHALF + (t + i * 512) * 8], B + offB[h][i]);
      offB[h][i] += 64;
    }
  };

  // loop-invariant read base pointers: slot XOR is lane-constant per ks
  const ushort_t* aB[2];
  const ushort_t* bB[2];
  #pragma unroll
  for (int ks = 0; ks < 2; ++ks) {
    aB[ks] = As + (wr * WM + r16) * 64 + (((ks * 4 + quad) ^ (r16 & 7)) << 3);
    bB[ks] = Bs + (wc * WN + r16) * 64 + (((ks * 4 + quad) ^ (r16 & 7)) << 3);
  }

  f32x4 acc[MI][NIfr] = {};
  bf16x8 aL[2][MH], aH[2][MH], bL[2][NH], bH[2][NH];

// reads: all offsets compile-time immediates off aB/bB
#define READ_AL(TO)                                                         \
  _Pragma("unroll") for (int ks = 0; ks < 2; ++ks)                          \
  _Pragma("unroll") for (int mi = 0; mi < MH; ++mi)                         \
      aL[ks][mi] = *(const bf16x8*)(aB[ks] + (TO) * AST + mi * 1024);
#define READ_AH(TO)                                                         \
  _Pragma("unroll") for (int ks = 0; ks < 2; ++ks)                          \
  _Pragma("unroll") for (int mi = 0; mi < MH; ++mi)                         \
      aH[ks][mi] = *(const bf16x8*)(aB[ks] + (TO) * AST + (MH + mi) * 1024);
#define READ_BL(TO)                                                         \
  _Pragma("unroll") for (int ks = 0; ks < 2; ++ks)                          \
  _Pragma("unroll") for (int ni = 0; ni < NH; ++ni)                         \
      bL[ks][ni] = *(const bf16x8*)(bB[ks] + (TO) * BST + ni * 1024);
#define READ_BH(TO)                                                         \
  _Pragma("unroll") for (int ks = 0; ks < 2; ++ks)                          \
  _Pragma("unroll") for (int ni = 0; ni < NH; ++ni)                         \
      bH[ks][ni] = *(const bf16x8*)(bB[ks] + (TO) * BST + (NH + ni) * 1024);
// one C-quadrant x K=64: ks-chained MFMA pairs
#define MMQ(MHI, NHI, AF, BF)                                               \
  __builtin_amdgcn_s_setprio(1);                                            \
  _Pragma("unroll") for (int mi = 0; mi < MH; ++mi)                         \
  _Pragma("unroll") for (int ni = 0; ni < NH; ++ni)                         \
  _Pragma("unroll") for (int ks = 0; ks < 2; ++ks)                          \
      acc[(MHI) * MH + mi][(NHI) * NH + ni] =                               \
          __builtin_amdgcn_mfma_f32_16x16x32_bf16(                          \
              AF[ks][mi], BF[ks][ni],                                       \
              acc[(MHI) * MH + mi][(NHI) * NH + ni], 0, 0, 0);              \
  __builtin_amdgcn_s_setprio(0);

  // prologue: E.Bh0, E.Bh1, E.Ah0, E.Ah1, O.Bh0, O.Bh1; leave O.B in flight
  stageB(0, 0); stageB(0, 1); stageA(0, 0); stageA(0, 1);
  stageB(1, 0); stageB(1, 1);
  waitv<2 * LB>();
  __builtin_amdgcn_s_barrier();

  const int NITER = K / 128;
  for (int it = 0; it < NITER; ++it) {
    const bool more = (it + 1 < NITER);
    // ===== K-tile E (buf 0): phases P1..P4 =====
    // P1 (q00)
    READ_AL(0); READ_BL(0);
    stageA(1, 0);
    __builtin_amdgcn_s_barrier();
    lgkm0();
    MMQ(0, 0, aL, bL);
    __builtin_amdgcn_s_barrier();
    // P2 (q01)
    READ_BH(0);
    stageA(1, 1);
    __builtin_amdgcn_s_barrier();
    lgkm0();
    MMQ(0, 1, aL, bH);
    __builtin_amdgcn_s_barrier();
    // P3 (q10)
    READ_AH(0);
    if (more) stageB(0, 0);
    __builtin_amdgcn_s_barrier();
    lgkm0();
    MMQ(1, 0, aH, bL);
    __builtin_amdgcn_s_barrier();
    // P4 (q11)
    if (more) stageB(0, 1);
    __builtin_amdgcn_s_barrier();
    MMQ(1, 1, aH, bH);
    if (more) waitv<2 * LB>(); else waitv<0>();
    __builtin_amdgcn_s_barrier();

    // ===== K-tile O (buf 1): phases P5..P8 =====
    // P5 (q00)
    READ_AL(1); READ_BL(1);
    if (more) stageA(0, 0);
    __builtin_amdgcn_s_barrier();
    lgkm0();
    MMQ(0, 0, aL, bL);
    __builtin_amdgcn_s_barrier();
    // P6 (q01)
    READ_BH(1);
    if (more) stageA(0, 1);
    __builtin_amdgcn_s_barrier();
    lgkm0();
    MMQ(0, 1, aL, bH);
    __builtin_amdgcn_s_barrier();
    // P7 (q10)
    READ_AH(1);
    if (more) stageB(1, 0);
    __builtin_amdgcn_s_barrier();
    lgkm0();
    MMQ(1, 0, aH, bL);
    __builtin_amdgcn_s_barrier();
    // P8 (q11)
    if (more) stageB(1, 1);
    __builtin_amdgcn_s_barrier();
    MMQ(1, 1, aH, bH);
    if (more) waitv<2 * LB>();
    __builtin_amdgcn_s_barrier();
  }

  // ---- epilogue: C/D layout col=lane&15, row=quad*4+reg ----
  float iv[MI][4];
  if constexpr (OUTMODE == OM_NORM) {
    #pragma unroll
    for (int mi = 0; mi < MI; ++mi)
      #pragma unroll
      for (int r = 0; r < 4; ++r)
        iv[mi][r] = invrs[rowBase + wr * WM + mi * 16 + quad * 4 + r];
  }

  float psum[MI][4];
  if constexpr (OUTMODE == OM_EXP) {
    #pragma unroll
    for (int mi = 0; mi < MI; ++mi)
      #pragma unroll
      for (int r = 0; r < 4; ++r) psum[mi][r] = 0.f;
  }

  #pragma unroll
  for (int mi = 0; mi < MI; ++mi)
    #pragma unroll
    for (int ni = 0; ni < NIfr; ++ni)
      #pragma unroll
      for (int r = 0; r < 4; ++r) {
        int grow = rowBase + wr * WM + mi * 16 + quad * 4 + r;
        int gcol = colBase + wc * WN + ni * 16 + r16;
        float a = acc[mi][ni][r];
        if constexpr (OUTMODE == OM_BF16) {
          ((ushort_t*)C)[(size_t)grow * ldc + gcol] = f2bf(a * scale);
        } else if constexpr (OUTMODE == OM_EXP) {
          float e = exp2f(a * scale);   // scale carries the log2(e) factor
          psum[mi][r] += e;
          ((ushort_t*)C)[(size_t)grow * ldc + gcol] = f2bf(e);
        } else {  // OM_NORM
          ((float*)C)[(size_t)grow * ldc + gcol] = a * iv[mi][r];
        }
      }

  if constexpr (OUTMODE == OM_EXP) {
    __syncthreads();                 // all LDS traffic done before reuse
    float* lds_rs = (float*)As;      // [4][256]
    #pragma unroll
    for (int mi = 0; mi < MI; ++mi)
      #pragma unroll
      for (int r = 0; r < 4; ++r) {
        float sv = psum[mi][r];
        sv += __shfl_xor(sv, 1, 64);
        sv += __shfl_xor(sv, 2, 64);
        sv += __shfl_xor(sv, 4, 64);
        sv += __shfl_xor(sv, 8, 64);
        if (r16 == 0)
          lds_rs[wc * 256 + wr * WM + mi * 16 + quad * 4 + r] = sv;
      }
    __syncthreads();
    if (t < 256)
      rsp[(size_t)nt * SEQ + rowBase + t] =
          lds_rs[t] + lds_rs[256 + t] + lds_rs[512 + t] + lds_rs[768 + t];
  }
#undef READ_AL
#undef READ_AH
#undef READ_BL
#undef READ_BH
#undef MMQ
}

extern "C" void kernel_launch(void* const* d_in, const int* in_sizes, int n_in,
                              void* d_out, int out_size, void* d_ws, size_t ws_size,
                              hipStream_t stream) {
  const float* x  = (const float*)d_in[0];
  const float* Wq = (const float*)d_in[1];
  const float* Wk = (const float*)d_in[2];
  const float* Wv = (const float*)d_in[3];
  float* out = (float*)d_out;

  char* p = (char*)d_ws;
  ushort_t* xb   = (ushort_t*)p; p += (size_t)SEQ * DIN * 2;        // 16 MB
  ushort_t* wqkb = (ushort_t*)p; p += (size_t)2 * DOUT * DIN * 2;   //  4 MB (Wq|Wk)
  ushort_t* wvb  = (ushort_t*)p; p += (size_t)DOUT * DIN * 2;       //  2 MB
  ushort_t* qkb  = (ushort_t*)p; p += (size_t)SEQ * 2 * DOUT * 2;   // 32 MB ([S][2048], q|k)
  ushort_t* vtb  = (ushort_t*)p; p += (size_t)DOUT * SEQ * 2;       // 16 MB (v^T)
  float*    rsp  = (float*)p;    p += (size_t)64 * SEQ * 4;         //  2 MB partial rowsums
  float*    irs  = (float*)p;    p += (size_t)SEQ * 4;              // 32 KB 1/rowsum
  ushort_t* Sb   = (ushort_t*)p; p += (size_t)SEQ * SEQ * 2;        // 128 MB

  // fp32 -> bf16 for all four tensors (one launch)
  cvt_all_kernel<<<8192 + 3 * 1024, 256, 0, stream>>>(x, Wq, Wk, Wv, xb, wqkb, wvb);

  dim3 blk(512);
  // [q|k] = x @ [Wq|Wk]^T : M=8192, N=2048, K=1024 -> 8x32 = 256 blocks
  gemmq<OM_BF16, 0, 256, 256><<<dim3(2048 / 256, SEQ / 256), blk, 0, stream>>>(
      xb, wqkb, qkb, DIN, DIN, 2 * DOUT, DIN, 1.0f, nullptr, nullptr);

  // v^T = Wv @ x^T : M=1024, N=8192, K=1024 -> BM=128: 32x8 = 256 blocks
  gemmq<OM_BF16, 0, 128, 256><<<dim3(SEQ / 256, DOUT / 128), blk, 0, stream>>>(
      wvb, xb, vtb, DIN, DIN, SEQ, DIN, 1.0f, nullptr, nullptr);

  // E = exp((q @ k^T)/32) via exp2, partial row sums -> rsp : 32x32 = 1024 blocks
  gemmq<OM_EXP, 1, 256, 256><<<dim3(SEQ / 256, SEQ / 256), blk, 0, stream>>>(
      qkb, qkb + DOUT, Sb, 2 * DOUT, 2 * DOUT, SEQ, DIN,
      0.03125f * 1.44269504f, rsp, nullptr);

  // invrs[r] = 1 / sum_p rsp[p][r]  (32 partial tiles)
  rowsum_inv_kernel<<<SEQ / 256, 256, 0, stream>>>(rsp, irs);

  // out = (E @ v) * invrs : M=8192, N=1024, K=8192 -> BN=128: 8x32 = 256 blocks
  gemmq<OM_NORM, 0, 256, 128><<<dim3(DOUT / 128, SEQ / 256), blk, 0, stream>>>(
      Sb, vtb, out, SEQ, SEQ, DOUT, SEQ, 1.0f, nullptr, irs);
}